// Round 8
// baseline (100.557 us; speedup 1.0000x reference)
//
#include <hip/hip_runtime.h>
#include <hip/hip_bf16.h>

// Problem constants (reference: B=2, S=2048, D=1024, H=16, HD=64)
constexpr int Bb = 2, Ss = 2048, Dd = 1024, Hh = 16, HD = 64;
constexpr int Mrows = Bb * Ss;                 // 4096
constexpr float QSCALE = 0.125f * 1.44269504088896f;  // 1/sqrt(HD) * log2(e), folded into Q
constexpr size_t CTX_ELEMS = (size_t)Bb * Hh * Ss * HD;   // 4194304

typedef __attribute__((ext_vector_type(8)))  short        short8;
typedef __attribute__((ext_vector_type(4)))  float        floatx4;
typedef __attribute__((ext_vector_type(16))) float        floatx16;
typedef __attribute__((ext_vector_type(4)))  unsigned int uintx4;
typedef __attribute__((ext_vector_type(8)))  __bf16       bf16x8;

#define DEVI __device__ __forceinline__

DEVI unsigned short f2bf(float f) {
  union { float f; unsigned u; } x; x.f = f;
  return (unsigned short)((x.u + 0x7fffu + ((x.u >> 16) & 1u)) >> 16);   // RNE
}
DEVI float fexp2(float x) {
#if __has_builtin(__builtin_amdgcn_exp2f)
  return __builtin_amdgcn_exp2f(x);
#else
  return __expf(x * 0.6931471805599453f);
#endif
}

// workspace layout (bf16-elem units), fast path:
constexpr size_t XE = (size_t)Mrows * Dd;      // 4M per X tensor
constexpr size_t WE = (size_t)Dd * Dd;         // 1M per W tensor
constexpr size_t OFF_W = 3 * XE;               // converted weights
constexpr size_t OFF_O = 3 * XE + 3 * WE;      // Q | K | V^T outputs
constexpr size_t WS_NEED = (OFF_O + 3 * XE) * 2;   // 54 MB
// kv-split partial buffers reuse the X-convert region (dead after GEMM):
constexpr size_t P0_E = 0;         // 4.19M f32 ctx partial (half 0) = 8.39M elems
constexpr size_t LA_E = 8388608;   // 65536 f32 lsum partial (half 0)
constexpr size_t LB_E = 8912896;   // 65536 f32 lsum partial (half 1)

// ---------------------------------------------------------------------------
// fp32 -> bf16 conversion pass (6 tensors)
// ---------------------------------------------------------------------------
__global__ __launch_bounds__(256) void convert_bf16(
    const float* __restrict__ q, const float* __restrict__ k, const float* __restrict__ v,
    const float* __restrict__ wq, const float* __restrict__ wk, const float* __restrict__ wv,
    unsigned short* __restrict__ dst)
{
  const int sel = blockIdx.y;
  const float* src; size_t n, off;
  switch (sel) {
    case 0:  src = q;  n = XE; off = 0;            break;
    case 1:  src = k;  n = XE; off = XE;           break;
    case 2:  src = v;  n = XE; off = 2 * XE;       break;
    case 3:  src = wq; n = WE; off = OFF_W;        break;
    case 4:  src = wk; n = WE; off = OFF_W + WE;   break;
    default: src = wv; n = WE; off = OFF_W + 2*WE; break;
  }
  unsigned short* d = dst + off;
  const size_t stride = (size_t)gridDim.x * blockDim.x;
  for (size_t i = (size_t)blockIdx.x * blockDim.x + threadIdx.x; i < n / 8; i += stride) {
    const floatx4 a = *(const floatx4*)(src + i * 8);
    const floatx4 b = *(const floatx4*)(src + i * 8 + 4);
    short8 o;
    #pragma unroll
    for (int j = 0; j < 4; ++j) { o[j] = (short)f2bf(a[j]); o[4 + j] = (short)f2bf(b[j]); }
    *(short8*)(d + i * 8) = o;
  }
}

// ---------------------------------------------------------------------------
// Shared GEMM epilogue (16x16 layout).
// ---------------------------------------------------------------------------
template<bool SWAP>
DEVI void store_out(floatx4 (&acc)[4][4], const float* __restrict__ bias,
                    unsigned short* __restrict__ out, float oscale,
                    int bm, int bn, int wm, int wn, int lrow, int lg)
{
  if constexpr (!SWAP) {
    #pragma unroll
    for (int ni = 0; ni < 4; ++ni) {
      const int gcol = bn * 128 + wn + ni * 16 + lrow;
      const float bval = bias[gcol];
      const int h = gcol >> 6, hd = gcol & 63;
      #pragma unroll
      for (int mi = 0; mi < 4; ++mi)
        #pragma unroll
        for (int r = 0; r < 4; ++r) {
          const int grow = bm * 128 + wm + mi * 16 + lg * 4 + r;   // = b*S + s
          const int b = grow >> 11, s = grow & 2047;
          out[(((size_t)(b * Hh + h) * Ss + s) << 6) + hd] = f2bf((acc[mi][ni][r] + bval) * oscale);
        }
    }
  } else {
    #pragma unroll
    for (int ni = 0; ni < 4; ++ni)
      #pragma unroll
      for (int r = 0; r < 4; ++r) {
        const int n = bn * 128 + wn + ni * 16 + lg * 4 + r;
        const float bval = bias[n];
        #pragma unroll
        for (int mi = 0; mi < 4; ++mi) {
          const int m = bm * 128 + wm + mi * 16 + lrow;
          out[(size_t)n * Mrows + m] = f2bf(acc[mi][ni][r] + bval);
        }
      }
  }
}

// ---------------------------------------------------------------------------
// Fast GEMM core: global_load_lds(16B), BK=64, XOR-swizzled LDS.
// ---------------------------------------------------------------------------
DEVI void gload16(const unsigned short* g, unsigned short* l) {
  __builtin_amdgcn_global_load_lds(
      (const __attribute__((address_space(1))) unsigned int*)g,
      (__attribute__((address_space(3))) unsigned int*)l, 16, 0, 0);
}

template<bool SWAP>
DEVI void gemm_core_bf16(const unsigned short* __restrict__ X,
                         const unsigned short* __restrict__ W,
                         const float* __restrict__ bias,
                         unsigned short* __restrict__ out, float oscale,
                         unsigned short* As, unsigned short* Bs, int bm, int bn)
{
  const int t = threadIdx.x, wid = t >> 6, lane = t & 63;
  const int lrow = lane & 15, lg = lane >> 4;
  const int wm = (wid >> 1) * 64, wn = (wid & 1) * 64;

  const int srow = lane >> 3;
  const int gch  = (lane & 7) ^ srow;
  const unsigned short* gA = X + (size_t)(bm * 128 + wid * 32 + srow) * Dd + gch * 8;
  const unsigned short* gB = W + (size_t)(bn * 128 + wid * 32 + srow) * Dd + gch * 8;
  unsigned short* lA = As + wid * 4 * 512;
  unsigned short* lB = Bs + wid * 4 * 512;

  floatx4 acc[4][4];
  #pragma unroll
  for (int i = 0; i < 4; ++i)
    #pragma unroll
    for (int j = 0; j < 4; ++j) acc[i][j] = 0.0f;

  for (int k0 = 0; k0 < Dd; k0 += 64) {
    __syncthreads();
    #pragma unroll
    for (int j = 0; j < 4; ++j) {
      gload16(gA + (size_t)j * 8 * Dd + k0, lA + j * 512);
      gload16(gB + (size_t)j * 8 * Dd + k0, lB + j * 512);
    }
    __syncthreads();

    #pragma unroll
    for (int kf = 0; kf < 2; ++kf) {
      bf16x8 af[4], bf[4];
      #pragma unroll
      for (int mi = 0; mi < 4; ++mi) {
        const int row = wm + mi * 16 + lrow;
        const int ch  = ((kf << 2) | lg) ^ (lrow & 7);
        af[mi] = __builtin_bit_cast(bf16x8, *(const short8*)&As[row * 64 + (ch << 3)]);
      }
      #pragma unroll
      for (int ni = 0; ni < 4; ++ni) {
        const int row = wn + ni * 16 + lrow;
        const int ch  = ((kf << 2) | lg) ^ (lrow & 7);
        bf[ni] = __builtin_bit_cast(bf16x8, *(const short8*)&Bs[row * 64 + (ch << 3)]);
      }
      #pragma unroll
      for (int mi = 0; mi < 4; ++mi)
        #pragma unroll
        for (int ni = 0; ni < 4; ++ni) {
          if constexpr (SWAP)
            acc[mi][ni] = __builtin_amdgcn_mfma_f32_16x16x32_bf16(bf[ni], af[mi], acc[mi][ni], 0, 0, 0);
          else
            acc[mi][ni] = __builtin_amdgcn_mfma_f32_16x16x32_bf16(af[mi], bf[ni], acc[mi][ni], 0, 0, 0);
        }
    }
  }
  store_out<SWAP>(acc, bias, out, oscale, bm, bn, wm, wn, lrow, lg);
}

__global__ __launch_bounds__(256, 3) void qkv_gemm_bf16(
    const unsigned short* __restrict__ ws,
    const float* __restrict__ bq, const float* __restrict__ bk, const float* __restrict__ bv,
    unsigned short* __restrict__ outbase)
{
  __shared__ __align__(16) unsigned short As[128 * 64];
  __shared__ __align__(16) unsigned short Bs[128 * 64];

  const int id  = blockIdx.y * 256 + blockIdx.x;
  const int swz = (id & 7) * 96 + (id >> 3);
  const int sel = swz >> 8;
  const int bx  = swz & 255;
  const int bm = bx >> 3, bn = bx & 7;

  const unsigned short* X = ws + (size_t)sel * XE;
  const unsigned short* W = ws + OFF_W + (size_t)sel * WE;
  const float* bias = sel == 0 ? bq : sel == 1 ? bk : bv;
  unsigned short* out = outbase + (size_t)sel * XE;

  if (sel == 2) gemm_core_bf16<true >(X, W, bias, out, 1.0f,   As, Bs, bm, bn);
  else          gemm_core_bf16<false>(X, W, bias, out, sel == 0 ? QSCALE : 1.0f, As, Bs, bm, bn);
}

// ---------------------------------------------------------------------------
// Fallback GEMM (fp32 inputs) — used if ws too small.
// ---------------------------------------------------------------------------
constexpr int APAD = 40;

template<bool SWAP>
DEVI void gemm_core_f32(const float* __restrict__ X, const float* __restrict__ W,
                        const float* __restrict__ bias, unsigned short* __restrict__ out,
                        float oscale, unsigned short* As, unsigned short* Bs, int bm, int bn)
{
  const int t = threadIdx.x, wid = t >> 6, lane = t & 63;
  const int lrow = lane & 15, lg = lane >> 4;
  const int wm = (wid >> 1) * 64, wn = (wid & 1) * 64;

  floatx4 acc[4][4];
  #pragma unroll
  for (int i = 0; i < 4; ++i)
    #pragma unroll
    for (int j = 0; j < 4; ++j) acc[i][j] = 0.0f;

  for (int k0 = 0; k0 < Dd; k0 += 32) {
    __syncthreads();
    #pragma unroll
    for (int half = 0; half < 2; ++half) {
      const int cidx = t + half * 256;
      const int r = cidx >> 2, c = cidx & 3;
      {
        const float* ga = X + (size_t)(bm * 128 + r) * Dd + k0 + c * 8;
        const floatx4 x0 = *(const floatx4*)ga;
        const floatx4 x1 = *(const floatx4*)(ga + 4);
        short8 va;
        #pragma unroll
        for (int j = 0; j < 4; ++j) { va[j] = (short)f2bf(x0[j]); va[4+j] = (short)f2bf(x1[j]); }
        *(short8*)&As[r * APAD + c * 8] = va;
      }
      {
        const float* gb = W + (size_t)(bn * 128 + r) * Dd + k0 + c * 8;
        const floatx4 x0 = *(const floatx4*)gb;
        const floatx4 x1 = *(const floatx4*)(gb + 4);
        short8 vb;
        #pragma unroll
        for (int j = 0; j < 4; ++j) { vb[j] = (short)f2bf(x0[j]); vb[4+j] = (short)f2bf(x1[j]); }
        *(short8*)&Bs[r * APAD + c * 8] = vb;
      }
    }
    __syncthreads();

    bf16x8 af[4], bf[4];
    #pragma unroll
    for (int mi = 0; mi < 4; ++mi)
      af[mi] = __builtin_bit_cast(bf16x8, *(const short8*)&As[(wm + mi * 16 + lrow) * APAD + lg * 8]);
    #pragma unroll
    for (int ni = 0; ni < 4; ++ni)
      bf[ni] = __builtin_bit_cast(bf16x8, *(const short8*)&Bs[(wn + ni * 16 + lrow) * APAD + lg * 8]);

    #pragma unroll
    for (int mi = 0; mi < 4; ++mi)
      #pragma unroll
      for (int ni = 0; ni < 4; ++ni) {
        if constexpr (SWAP)
          acc[mi][ni] = __builtin_amdgcn_mfma_f32_16x16x32_bf16(bf[ni], af[mi], acc[mi][ni], 0, 0, 0);
        else
          acc[mi][ni] = __builtin_amdgcn_mfma_f32_16x16x32_bf16(af[mi], bf[ni], acc[mi][ni], 0, 0, 0);
      }
  }
  store_out<SWAP>(acc, bias, out, oscale, bm, bn, wm, wn, lrow, lg);
}

__global__ __launch_bounds__(256, 2) void qkv_gemm_f32(
    const float* __restrict__ q, const float* __restrict__ k, const float* __restrict__ v,
    const float* __restrict__ wq, const float* __restrict__ wk, const float* __restrict__ wv,
    const float* __restrict__ bq, const float* __restrict__ bk, const float* __restrict__ bv,
    unsigned short* __restrict__ outbase)
{
  __shared__ __align__(16) unsigned short As[128 * APAD];
  __shared__ __align__(16) unsigned short Bs[128 * APAD];

  const int id  = blockIdx.y * 256 + blockIdx.x;
  const int swz = (id & 7) * 96 + (id >> 3);
  const int sel = swz >> 8;
  const int bx  = swz & 255;
  const int bm = bx >> 3, bn = bx & 7;

  const float* X = sel == 0 ? q : sel == 1 ? k : v;
  const float* W = sel == 0 ? wq : sel == 1 ? wk : wv;
  const float* bias = sel == 0 ? bq : sel == 1 ? bk : bv;
  unsigned short* out = outbase + (size_t)sel * XE;

  if (sel == 2) gemm_core_f32<true >(X, W, bias, out, 1.0f, As, Bs, bm, bn);
  else          gemm_core_f32<false>(X, W, bias, out, sel == 0 ? QSCALE : 1.0f, As, Bs, bm, bn);
}

// ---------------------------------------------------------------------------
// Flash attention, 32x32 MFMA, LDS-staged, in-register softmax.
// SPLIT=true : kv-split x2 (1024 blocks, 4/CU = 4 waves/SIMD). Each half
//   writes UNNORMALIZED f32 ctx partial + per-q lsum partial (additive since
//   softmax has no running max).  half0 -> ws X-region, half1 -> out ctx region.
// SPLIT=false: fallback, full kv, normalizes in-kernel (LDS lsum redistribute).
// lsum via VALU per-lane column sum (P row is lane-local) — saves the 4
// ones-MFMA per tile (-20% MFMA work).
// permlane32_swap semantics (verified by the P-build): a keeps lo lanes, a_hi
// receives b_lo; b_lo receives a_hi, b keeps hi lanes.  So the PARTNER value
// is in sb for hi=0 lanes and in sa for hi=1 lanes.
// ---------------------------------------------------------------------------
template<bool SPLIT>
__global__ __launch_bounds__(256, 4) void attn_fwd(
    const unsigned short* __restrict__ Qw, const unsigned short* __restrict__ Kw,
    const unsigned short* __restrict__ Vw,
    float* __restrict__ p0, float* __restrict__ la,
    float* __restrict__ p1, float* __restrict__ lb,
    float* __restrict__ out)
{
  __shared__ __align__(16) unsigned short Ks[2][64 * 64];   // [kv][hd], chunk^=(kv&7)
  __shared__ __align__(16) unsigned short Vt[2][64 * 64];   // [hd][kv], chunk^=(hd&7)
  __shared__ float Ld[4][32];                               // fallback lsum redistribute

  int kh, qb, bh, ntiles;
  if constexpr (SPLIT) {
    const int id  = blockIdx.y * 32 + blockIdx.x;           // 1024 blocks
    const int swz = (id & 7) * 128 + (id >> 3);             // XCD-bijective
    kh = swz & 1; qb = (swz >> 1) & 15; bh = swz >> 5;
    ntiles = 16;
  } else {
    const int id  = blockIdx.y * 16 + blockIdx.x;           // 512 blocks
    const int swz = (id & 7) * 64 + (id >> 3);
    kh = 0; qb = swz & 15; bh = swz >> 4;
    ntiles = 32;
  }
  const int kvbase = kh * 1024;
  const int b = bh >> 4, h = bh & 15;

  const int t = threadIdx.x, wid = t >> 6, lane = t & 63;
  const int l31 = lane & 31, hi = lane >> 5;
  const unsigned short* Qb = Qw + (size_t)bh * (Ss * HD);
  const unsigned short* Kb = Kw + (size_t)bh * (Ss * HD);
  const unsigned short* Vg = Vw + (size_t)(h * 64) * Mrows + b * Ss;   // row=hd
  const int q0 = qb * 128 + wid * 32;

  // Q B-fragments: lane holds Q[q=l31][hd = hs*16 + hi*8 + j]
  bf16x8 qf[4];
  #pragma unroll
  for (int hs = 0; hs < 4; ++hs)
    qf[hs] = __builtin_bit_cast(bf16x8,
        *(const short8*)(Qb + (size_t)(q0 + l31) * 64 + hs * 16 + hi * 8));

  floatx16 ctx[2];
  ctx[0] = 0.0f; ctx[1] = 0.0f;
  float lsumv = 0.0f;                        // per-lane column sum (q = l31, my hi-half rows)

  // Staging: wave wid covers rows wid*16 .. wid*16+15 of both tensors.
  const int rl = lane >> 3;                  // 0..7 within 8-row group
  const int cs = (lane & 7) ^ rl;            // pre-swizzled source chunk
  auto stage = [&](int T) {                  // tile T (0..ntiles-1) -> buf T&1
    const int kv0 = kvbase + T * 64, buf = T & 1;
    #pragma unroll
    for (int i = 0; i < 2; ++i) {
      const int row = wid * 16 + i * 8 + rl;
      gload16(Kb + (size_t)(kv0 + row) * 64 + cs * 8, &Ks[buf][(wid * 16 + i * 8) * 64]);
      gload16(Vg + (size_t)row * Mrows + kv0 + cs * 8, &Vt[buf][(wid * 16 + i * 8) * 64]);
    }
  };

  stage(0);

  for (int it = 0; it < ntiles; ++it) {
    const int cur = it & 1;
    __syncthreads();                         // staged tile visible; prev buf free
    if (it + 1 < ntiles) stage(it + 1);

    // One kvb (32 kv rows) at a time: QK -> softmax -> PV (lower reg pressure;
    // 4 waves/SIMD hides the shorter MFMA chains).
    #pragma unroll
    for (int kvb = 0; kvb < 2; ++kvb) {
      floatx16 s = 0.0f;
      __builtin_amdgcn_s_setprio(1);
      #pragma unroll
      for (int hs = 0; hs < 4; ++hs) {
        const int ch = ((hs << 1) | hi) ^ (l31 & 7);
        const bf16x8 kf = __builtin_bit_cast(bf16x8,
            *(const short8*)&Ks[cur][(kvb * 32 + l31) * 64 + (ch << 3)]);
        s = __builtin_amdgcn_mfma_f32_32x32x16_bf16(kf, qf[hs], s, 0, 0, 0);
      }
      __builtin_amdgcn_s_setprio(0);

      float p[16];
      #pragma unroll
      for (int r = 0; r < 16; ++r) { p[r] = fexp2(s[r]); lsumv += p[r]; }
      unsigned int c[8];
      #pragma unroll
      for (int i = 0; i < 8; ++i)
        asm("v_cvt_pk_bf16_f32 %0, %1, %2" : "=v"(c[i]) : "v"(p[2 * i]), "v"(p[2 * i + 1]));

      #pragma unroll
      for (int ks2 = 0; ks2 < 2; ++ks2) {
        unsigned int w0 = c[4 * ks2 + 0], w2 = c[4 * ks2 + 2];
        unsigned int w1 = c[4 * ks2 + 1], w3 = c[4 * ks2 + 3];
        asm("v_permlane32_swap_b32 %0, %1" : "+v"(w0), "+v"(w2));
        asm("v_permlane32_swap_b32 %0, %1" : "+v"(w1), "+v"(w3));
        uintx4 paw; paw[0] = w0; paw[1] = w1; paw[2] = w2; paw[3] = w3;
        const bf16x8 pa = __builtin_bit_cast(bf16x8, paw);

        const int ks = kvb * 2 + ks2;        // 16-kv step within tile
        __builtin_amdgcn_s_setprio(1);
        #pragma unroll
        for (int nb = 0; nb < 2; ++nb) {
          const int ch = ((ks << 1) | hi) ^ (l31 & 7);
          const bf16x8 vf = __builtin_bit_cast(bf16x8,
              *(const short8*)&Vt[cur][(nb * 32 + l31) * 64 + (ch << 3)]);
          ctx[nb] = __builtin_amdgcn_mfma_f32_32x32x16_bf16(pa, vf, ctx[nb], 0, 0, 0);
        }
        __builtin_amdgcn_s_setprio(0);
      }
    }
  }

  // ---- lsum: combine hi halves.  After swap with sa=sb=lsumv:
  //   sa_hi <- sb_lo (partner for hi=1),  sb_lo <- sa_hi (partner for hi=0).
  float sa = lsumv, sb = lsumv;
  asm("v_permlane32_swap_b32 %0, %1" : "+v"(sa), "+v"(sb));
  const float tot = lsumv + (hi ? sa : sb);   // own half + partner half

  if constexpr (SPLIT) {
    float* lx = kh ? lb : la;
    if (hi == 0) lx[bh * Ss + q0 + l31] = tot;
    float* dst = kh ? p1 : p0;
    #pragma unroll
    for (int r = 0; r < 16; ++r) {
      const int qrow = q0 + (r & 3) + 8 * (r >> 2) + 4 * hi;
      #pragma unroll
      for (int nb = 0; nb < 2; ++nb)
        dst[((size_t)bh * Ss + qrow) * 64 + nb * 32 + l31] = ctx[nb][r];
    }
  } else {
    // redistribute per-column lsum to C-row layout via wave-local LDS
    if (hi == 0) Ld[wid][l31] = tot;
    #pragma unroll
    for (int r = 0; r < 16; ++r) {
      const int wr = (r & 3) + 8 * (r >> 2) + 4 * hi;
      const float inv = 1.0f / Ld[wid][wr];
      const int qrow = q0 + wr;
      #pragma unroll
      for (int nb = 0; nb < 2; ++nb) {
        const int hd = nb * 32 + l31;
        const float val = ctx[nb][r] * inv;
        out[((size_t)bh * Ss + qrow) * 64 + hd] = val;
        out[CTX_ELEMS + (((size_t)(b * Ss + qrow)) << 10) + (h << 6) + hd] = val;
      }
    }
  }
}

// ---------------------------------------------------------------------------
// Combine: ctx = (P0 + P1) / (LA + LB); write ctx [B,H,S,HD] and attn [B,S,D].
// P1 lives in the out ctx region (read-then-write same element, no aliasing).
// ---------------------------------------------------------------------------
__global__ __launch_bounds__(256) void combine_halves(
    const float* __restrict__ p0, const float* __restrict__ la,
    const float* __restrict__ lb, float* __restrict__ out)
{
  const size_t i4   = (size_t)blockIdx.x * 256 + threadIdx.x;
  const size_t base = i4 * 4;                       // 4 consecutive hd, same q
  const floatx4 a = *(const floatx4*)(p0 + base);
  const floatx4 c = *(const floatx4*)(out + base);
  const int q  = (int)(base >> 6);                  // bh*S + s
  const float inv = 1.0f / (la[q] + lb[q]);
  floatx4 v;
  #pragma unroll
  for (int j = 0; j < 4; ++j) v[j] = (a[j] + c[j]) * inv;
  *(floatx4*)(out + base) = v;
  const int bh = q >> 11, s = q & 2047, hd = (int)(base & 63);
  const int b = bh >> 4, h = bh & 15;
  *(floatx4*)(out + CTX_ELEMS + (((size_t)(b * Ss + s)) << 10) + (h << 6) + hd) = v;
}

// ---------------------------------------------------------------------------
extern "C" void kernel_launch(void* const* d_in, const int* in_sizes, int n_in,
                              void* d_out, int out_size, void* d_ws, size_t ws_size,
                              hipStream_t stream) {
  const float* q  = (const float*)d_in[0];
  const float* k  = (const float*)d_in[1];
  const float* v  = (const float*)d_in[2];
  const float* wq = (const float*)d_in[3];
  const float* bq = (const float*)d_in[4];
  const float* wk = (const float*)d_in[5];
  const float* bk = (const float*)d_in[6];
  const float* wv = (const float*)d_in[7];
  const float* bv = (const float*)d_in[8];
  unsigned short* ws = (unsigned short*)d_ws;
  float* out = (float*)d_out;

  if (ws_size >= WS_NEED) {
    convert_bf16<<<dim3(256, 6), 256, 0, stream>>>(q, k, v, wq, wk, wv, ws);
    qkv_gemm_bf16<<<dim3(256, 3), 256, 0, stream>>>(ws, bq, bk, bv, ws + OFF_O);
    float* P0 = (float*)(ws + P0_E);   // X-convert region is dead after GEMM
    float* LA = (float*)(ws + LA_E);
    float* LB = (float*)(ws + LB_E);
    attn_fwd<true><<<dim3(32, 32), 256, 0, stream>>>(
        ws + OFF_O, ws + OFF_O + XE, ws + OFF_O + 2 * XE, P0, LA, out, LB, out);
    combine_halves<<<(int)(CTX_ELEMS / 1024), 256, 0, stream>>>(P0, LA, LB, out);
  } else {
    qkv_gemm_f32<<<dim3(256, 3), 256, 0, stream>>>(q, k, v, wq, wk, wv, bq, bk, bv, ws);
    attn_fwd<false><<<dim3(16, 32), 256, 0, stream>>>(
        ws, ws + XE, ws + 2 * XE, nullptr, nullptr, nullptr, nullptr, out);
  }
}

// Round 9
// 88.841 us; speedup vs baseline: 1.1319x; 1.1319x over previous
//
#include <hip/hip_runtime.h>
#include <hip/hip_bf16.h>

// Problem constants (reference: B=2, S=2048, D=1024, H=16, HD=64)
constexpr int Bb = 2, Ss = 2048, Dd = 1024, Hh = 16, HD = 64;
constexpr int Mrows = Bb * Ss;                 // 4096
constexpr float QSCALE = 0.125f * 1.44269504088896f;  // 1/sqrt(HD) * log2(e), folded into Q
constexpr size_t CTX_ELEMS = (size_t)Bb * Hh * Ss * HD;   // 4194304

typedef __attribute__((ext_vector_type(8)))  short        short8;
typedef __attribute__((ext_vector_type(4)))  float        floatx4;
typedef __attribute__((ext_vector_type(16))) float        floatx16;
typedef __attribute__((ext_vector_type(4)))  unsigned int uintx4;
typedef __attribute__((ext_vector_type(8)))  __bf16       bf16x8;

#define DEVI __device__ __forceinline__

DEVI unsigned short f2bf(float f) {
  union { float f; unsigned u; } x; x.f = f;
  return (unsigned short)((x.u + 0x7fffu + ((x.u >> 16) & 1u)) >> 16);   // RNE
}
DEVI float fexp2(float x) {
#if __has_builtin(__builtin_amdgcn_exp2f)
  return __builtin_amdgcn_exp2f(x);
#else
  return __expf(x * 0.6931471805599453f);
#endif
}

// workspace layout (bf16-elem units), fast path:
constexpr size_t XE = (size_t)Mrows * Dd;      // 4M per X tensor
constexpr size_t WE = (size_t)Dd * Dd;         // 1M per W tensor
constexpr size_t OFF_W = 3 * XE;               // converted weights
constexpr size_t OFF_O = 3 * XE + 3 * WE;      // Q | K | V^T outputs
constexpr size_t WS_NEED = (OFF_O + 3 * XE) * 2;   // 54 MB

// ---------------------------------------------------------------------------
// fp32 -> bf16 conversion pass (6 tensors)
// ---------------------------------------------------------------------------
__global__ __launch_bounds__(256) void convert_bf16(
    const float* __restrict__ q, const float* __restrict__ k, const float* __restrict__ v,
    const float* __restrict__ wq, const float* __restrict__ wk, const float* __restrict__ wv,
    unsigned short* __restrict__ dst)
{
  const int sel = blockIdx.y;
  const float* src; size_t n, off;
  switch (sel) {
    case 0:  src = q;  n = XE; off = 0;            break;
    case 1:  src = k;  n = XE; off = XE;           break;
    case 2:  src = v;  n = XE; off = 2 * XE;       break;
    case 3:  src = wq; n = WE; off = OFF_W;        break;
    case 4:  src = wk; n = WE; off = OFF_W + WE;   break;
    default: src = wv; n = WE; off = OFF_W + 2*WE; break;
  }
  unsigned short* d = dst + off;
  const size_t stride = (size_t)gridDim.x * blockDim.x;
  for (size_t i = (size_t)blockIdx.x * blockDim.x + threadIdx.x; i < n / 8; i += stride) {
    const floatx4 a = *(const floatx4*)(src + i * 8);
    const floatx4 b = *(const floatx4*)(src + i * 8 + 4);
    short8 o;
    #pragma unroll
    for (int j = 0; j < 4; ++j) { o[j] = (short)f2bf(a[j]); o[4 + j] = (short)f2bf(b[j]); }
    *(short8*)(d + i * 8) = o;
  }
}

// ---------------------------------------------------------------------------
// Shared GEMM epilogue (16x16 layout).
// ---------------------------------------------------------------------------
template<bool SWAP>
DEVI void store_out(floatx4 (&acc)[4][4], const float* __restrict__ bias,
                    unsigned short* __restrict__ out, float oscale,
                    int bm, int bn, int wm, int wn, int lrow, int lg)
{
  if constexpr (!SWAP) {
    #pragma unroll
    for (int ni = 0; ni < 4; ++ni) {
      const int gcol = bn * 128 + wn + ni * 16 + lrow;
      const float bval = bias[gcol];
      const int h = gcol >> 6, hd = gcol & 63;
      #pragma unroll
      for (int mi = 0; mi < 4; ++mi)
        #pragma unroll
        for (int r = 0; r < 4; ++r) {
          const int grow = bm * 128 + wm + mi * 16 + lg * 4 + r;   // = b*S + s
          const int b = grow >> 11, s = grow & 2047;
          out[(((size_t)(b * Hh + h) * Ss + s) << 6) + hd] = f2bf((acc[mi][ni][r] + bval) * oscale);
        }
    }
  } else {
    #pragma unroll
    for (int ni = 0; ni < 4; ++ni)
      #pragma unroll
      for (int r = 0; r < 4; ++r) {
        const int n = bn * 128 + wn + ni * 16 + lg * 4 + r;
        const float bval = bias[n];
        #pragma unroll
        for (int mi = 0; mi < 4; ++mi) {
          const int m = bm * 128 + wm + mi * 16 + lrow;
          out[(size_t)n * Mrows + m] = f2bf(acc[mi][ni][r] + bval);
        }
      }
  }
}

// ---------------------------------------------------------------------------
// Fast GEMM core: global_load_lds(16B), BK=64, XOR-swizzled LDS.
// ---------------------------------------------------------------------------
DEVI void gload16(const unsigned short* g, unsigned short* l) {
  __builtin_amdgcn_global_load_lds(
      (const __attribute__((address_space(1))) unsigned int*)g,
      (__attribute__((address_space(3))) unsigned int*)l, 16, 0, 0);
}

template<bool SWAP>
DEVI void gemm_core_bf16(const unsigned short* __restrict__ X,
                         const unsigned short* __restrict__ W,
                         const float* __restrict__ bias,
                         unsigned short* __restrict__ out, float oscale,
                         unsigned short* As, unsigned short* Bs, int bm, int bn)
{
  const int t = threadIdx.x, wid = t >> 6, lane = t & 63;
  const int lrow = lane & 15, lg = lane >> 4;
  const int wm = (wid >> 1) * 64, wn = (wid & 1) * 64;

  const int srow = lane >> 3;
  const int gch  = (lane & 7) ^ srow;
  const unsigned short* gA = X + (size_t)(bm * 128 + wid * 32 + srow) * Dd + gch * 8;
  const unsigned short* gB = W + (size_t)(bn * 128 + wid * 32 + srow) * Dd + gch * 8;
  unsigned short* lA = As + wid * 4 * 512;
  unsigned short* lB = Bs + wid * 4 * 512;

  floatx4 acc[4][4];
  #pragma unroll
  for (int i = 0; i < 4; ++i)
    #pragma unroll
    for (int j = 0; j < 4; ++j) acc[i][j] = 0.0f;

  for (int k0 = 0; k0 < Dd; k0 += 64) {
    __syncthreads();
    #pragma unroll
    for (int j = 0; j < 4; ++j) {
      gload16(gA + (size_t)j * 8 * Dd + k0, lA + j * 512);
      gload16(gB + (size_t)j * 8 * Dd + k0, lB + j * 512);
    }
    __syncthreads();

    #pragma unroll
    for (int kf = 0; kf < 2; ++kf) {
      bf16x8 af[4], bf[4];
      #pragma unroll
      for (int mi = 0; mi < 4; ++mi) {
        const int row = wm + mi * 16 + lrow;
        const int ch  = ((kf << 2) | lg) ^ (lrow & 7);
        af[mi] = __builtin_bit_cast(bf16x8, *(const short8*)&As[row * 64 + (ch << 3)]);
      }
      #pragma unroll
      for (int ni = 0; ni < 4; ++ni) {
        const int row = wn + ni * 16 + lrow;
        const int ch  = ((kf << 2) | lg) ^ (lrow & 7);
        bf[ni] = __builtin_bit_cast(bf16x8, *(const short8*)&Bs[row * 64 + (ch << 3)]);
      }
      #pragma unroll
      for (int mi = 0; mi < 4; ++mi)
        #pragma unroll
        for (int ni = 0; ni < 4; ++ni) {
          if constexpr (SWAP)
            acc[mi][ni] = __builtin_amdgcn_mfma_f32_16x16x32_bf16(bf[ni], af[mi], acc[mi][ni], 0, 0, 0);
          else
            acc[mi][ni] = __builtin_amdgcn_mfma_f32_16x16x32_bf16(af[mi], bf[ni], acc[mi][ni], 0, 0, 0);
        }
    }
  }
  store_out<SWAP>(acc, bias, out, oscale, bm, bn, wm, wn, lrow, lg);
}

__global__ __launch_bounds__(256, 3) void qkv_gemm_bf16(
    const unsigned short* __restrict__ ws,
    const float* __restrict__ bq, const float* __restrict__ bk, const float* __restrict__ bv,
    unsigned short* __restrict__ outbase)
{
  __shared__ __align__(16) unsigned short As[128 * 64];
  __shared__ __align__(16) unsigned short Bs[128 * 64];

  const int id  = blockIdx.y * 256 + blockIdx.x;
  const int swz = (id & 7) * 96 + (id >> 3);
  const int sel = swz >> 8;
  const int bx  = swz & 255;
  const int bm = bx >> 3, bn = bx & 7;

  const unsigned short* X = ws + (size_t)sel * XE;
  const unsigned short* W = ws + OFF_W + (size_t)sel * WE;
  const float* bias = sel == 0 ? bq : sel == 1 ? bk : bv;
  unsigned short* out = outbase + (size_t)sel * XE;

  if (sel == 2) gemm_core_bf16<true >(X, W, bias, out, 1.0f,   As, Bs, bm, bn);
  else          gemm_core_bf16<false>(X, W, bias, out, sel == 0 ? QSCALE : 1.0f, As, Bs, bm, bn);
}

// ---------------------------------------------------------------------------
// Fallback GEMM (fp32 inputs) — used if ws too small.
// ---------------------------------------------------------------------------
constexpr int APAD = 40;

template<bool SWAP>
DEVI void gemm_core_f32(const float* __restrict__ X, const float* __restrict__ W,
                        const float* __restrict__ bias, unsigned short* __restrict__ out,
                        float oscale, unsigned short* As, unsigned short* Bs, int bm, int bn)
{
  const int t = threadIdx.x, wid = t >> 6, lane = t & 63;
  const int lrow = lane & 15, lg = lane >> 4;
  const int wm = (wid >> 1) * 64, wn = (wid & 1) * 64;

  floatx4 acc[4][4];
  #pragma unroll
  for (int i = 0; i < 4; ++i)
    #pragma unroll
    for (int j = 0; j < 4; ++j) acc[i][j] = 0.0f;

  for (int k0 = 0; k0 < Dd; k0 += 32) {
    __syncthreads();
    #pragma unroll
    for (int half = 0; half < 2; ++half) {
      const int cidx = t + half * 256;
      const int r = cidx >> 2, c = cidx & 3;
      {
        const float* ga = X + (size_t)(bm * 128 + r) * Dd + k0 + c * 8;
        const floatx4 x0 = *(const floatx4*)ga;
        const floatx4 x1 = *(const floatx4*)(ga + 4);
        short8 va;
        #pragma unroll
        for (int j = 0; j < 4; ++j) { va[j] = (short)f2bf(x0[j]); va[4+j] = (short)f2bf(x1[j]); }
        *(short8*)&As[r * APAD + c * 8] = va;
      }
      {
        const float* gb = W + (size_t)(bn * 128 + r) * Dd + k0 + c * 8;
        const floatx4 x0 = *(const floatx4*)gb;
        const floatx4 x1 = *(const floatx4*)(gb + 4);
        short8 vb;
        #pragma unroll
        for (int j = 0; j < 4; ++j) { vb[j] = (short)f2bf(x0[j]); vb[4+j] = (short)f2bf(x1[j]); }
        *(short8*)&Bs[r * APAD + c * 8] = vb;
      }
    }
    __syncthreads();

    bf16x8 af[4], bf[4];
    #pragma unroll
    for (int mi = 0; mi < 4; ++mi)
      af[mi] = __builtin_bit_cast(bf16x8, *(const short8*)&As[(wm + mi * 16 + lrow) * APAD + lg * 8]);
    #pragma unroll
    for (int ni = 0; ni < 4; ++ni)
      bf[ni] = __builtin_bit_cast(bf16x8, *(const short8*)&Bs[(wn + ni * 16 + lrow) * APAD + lg * 8]);

    #pragma unroll
    for (int mi = 0; mi < 4; ++mi)
      #pragma unroll
      for (int ni = 0; ni < 4; ++ni) {
        if constexpr (SWAP)
          acc[mi][ni] = __builtin_amdgcn_mfma_f32_16x16x32_bf16(bf[ni], af[mi], acc[mi][ni], 0, 0, 0);
        else
          acc[mi][ni] = __builtin_amdgcn_mfma_f32_16x16x32_bf16(af[mi], bf[ni], acc[mi][ni], 0, 0, 0);
      }
  }
  store_out<SWAP>(acc, bias, out, oscale, bm, bn, wm, wn, lrow, lg);
}

__global__ __launch_bounds__(256, 2) void qkv_gemm_f32(
    const float* __restrict__ q, const float* __restrict__ k, const float* __restrict__ v,
    const float* __restrict__ wq, const float* __restrict__ wk, const float* __restrict__ wv,
    const float* __restrict__ bq, const float* __restrict__ bk, const float* __restrict__ bv,
    unsigned short* __restrict__ outbase)
{
  __shared__ __align__(16) unsigned short As[128 * APAD];
  __shared__ __align__(16) unsigned short Bs[128 * APAD];

  const int id  = blockIdx.y * 256 + blockIdx.x;
  const int swz = (id & 7) * 96 + (id >> 3);
  const int sel = swz >> 8;
  const int bx  = swz & 255;
  const int bm = bx >> 3, bn = bx & 7;

  const float* X = sel == 0 ? q : sel == 1 ? k : v;
  const float* W = sel == 0 ? wq : sel == 1 ? wk : wv;
  const float* bias = sel == 0 ? bq : sel == 1 ? bk : bv;
  unsigned short* out = outbase + (size_t)sel * XE;

  if (sel == 2) gemm_core_f32<true >(X, W, bias, out, 1.0f, As, Bs, bm, bn);
  else          gemm_core_f32<false>(X, W, bias, out, sel == 0 ? QSCALE : 1.0f, As, Bs, bm, bn);
}

// ---------------------------------------------------------------------------
// Flash attention, 8-wave in-block kv-split.
// Block = 512 threads: waves 0-3 do kv[0,1024) for 128 q-rows, waves 4-7 do
// kv[1024,2048) for the SAME q-rows.  Each half double-buffers its own 16 KB
// K / V^T LDS tiles (64 KB total -> 2 blocks/CU, 16 waves/CU).
// Epilogue: barrier -> half-1 dumps ctx+lsum to LDS (overlaid on dead staging
// buffers) -> barrier -> half-0 adds, normalizes, writes both outputs.
// No global partials, no combine kernel (round-8's 13 us combine eliminated).
// permlane32_swap: a keeps lo lanes, a_hi <- b_lo; b_lo <- a_hi, b keeps hi.
// ---------------------------------------------------------------------------
__global__ __launch_bounds__(512, 4) void attn_fwd8(
    const unsigned short* __restrict__ Qw, const unsigned short* __restrict__ Kw,
    const unsigned short* __restrict__ Vw, float* __restrict__ out)
{
  __shared__ __align__(16) char smemRaw[65536];
  unsigned short* KsB = (unsigned short*)smemRaw;             // [kh][buf][64*64]
  unsigned short* VtB = (unsigned short*)(smemRaw + 32768);   // [kh][buf][64*64]
  float* ctxL  = (float*)smemRaw;                             // epilogue overlay (32 KB)
  float* lsumL = (float*)(smemRaw + 32768);                   // epilogue overlay

  // XCD-bijective swizzle: 512 blocks -> 64-contiguous per XCD.
  const int id  = blockIdx.y * 16 + blockIdx.x;
  const int swz = (id & 7) * 64 + (id >> 3);
  const int qb  = swz & 15, bh = swz >> 4;
  const int b   = bh >> 4, h = bh & 15;

  const int t = threadIdx.x, wid8 = t >> 6, lane = t & 63;
  const int kh = wid8 >> 2, wid = wid8 & 3;    // kv-half, wave-within-half
  const int l31 = lane & 31, hi = lane >> 5;
  const int kvbase = kh << 10;
  const unsigned short* Qb = Qw + (size_t)bh * (Ss * HD);
  const unsigned short* Kb = Kw + (size_t)bh * (Ss * HD);
  const unsigned short* Vg = Vw + (size_t)(h * 64) * Mrows + b * Ss;   // row=hd
  const int q0 = qb * 128 + wid * 32;

  // Q B-fragments: lane holds Q[q=l31][hd = hs*16 + hi*8 + j]
  bf16x8 qf[4];
  #pragma unroll
  for (int hs = 0; hs < 4; ++hs)
    qf[hs] = __builtin_bit_cast(bf16x8,
        *(const short8*)(Qb + (size_t)(q0 + l31) * 64 + hs * 16 + hi * 8));

  floatx16 ctx[2];
  ctx[0] = 0.0f; ctx[1] = 0.0f;
  float lsumv = 0.0f;                        // per-lane column sum (q = l31, my hi-half rows)

  // Staging: wave (kh,wid) covers rows wid*16 .. wid*16+15 of its half's tile.
  const int rl = lane >> 3;                  // 0..7 within 8-row group
  const int cs = (lane & 7) ^ rl;            // pre-swizzled source chunk
  auto stage = [&](int T) {                  // tile T (0..15) -> buf T&1 of half kh
    const int kv0 = kvbase + T * 64;
    unsigned short* Kd = KsB + (size_t)(kh * 2 + (T & 1)) * 4096;
    unsigned short* Vd = VtB + (size_t)(kh * 2 + (T & 1)) * 4096;
    #pragma unroll
    for (int i = 0; i < 2; ++i) {
      const int row = wid * 16 + i * 8 + rl;
      gload16(Kb + (size_t)(kv0 + row) * 64 + cs * 8, Kd + (wid * 16 + i * 8) * 64);
      gload16(Vg + (size_t)row * Mrows + kv0 + cs * 8, Vd + (wid * 16 + i * 8) * 64);
    }
  };

  stage(0);

  for (int it = 0; it < 16; ++it) {
    const int cur = it & 1;
    __syncthreads();                         // staged tile visible; prev buf free
    if (it + 1 < 16) stage(it + 1);
    const unsigned short* Kc = KsB + (size_t)(kh * 2 + cur) * 4096;
    const unsigned short* Vc = VtB + (size_t)(kh * 2 + cur) * 4096;

    #pragma unroll
    for (int kvb = 0; kvb < 2; ++kvb) {
      floatx16 s = 0.0f;
      __builtin_amdgcn_s_setprio(1);
      #pragma unroll
      for (int hs = 0; hs < 4; ++hs) {
        const int ch = ((hs << 1) | hi) ^ (l31 & 7);
        const bf16x8 kf = __builtin_bit_cast(bf16x8,
            *(const short8*)&Kc[(kvb * 32 + l31) * 64 + (ch << 3)]);
        s = __builtin_amdgcn_mfma_f32_32x32x16_bf16(kf, qf[hs], s, 0, 0, 0);
      }
      __builtin_amdgcn_s_setprio(0);

      float p[16];
      #pragma unroll
      for (int r = 0; r < 16; ++r) { p[r] = fexp2(s[r]); lsumv += p[r]; }
      unsigned int c[8];
      #pragma unroll
      for (int i = 0; i < 8; ++i)
        asm("v_cvt_pk_bf16_f32 %0, %1, %2" : "=v"(c[i]) : "v"(p[2 * i]), "v"(p[2 * i + 1]));

      #pragma unroll
      for (int ks2 = 0; ks2 < 2; ++ks2) {
        unsigned int w0 = c[4 * ks2 + 0], w2 = c[4 * ks2 + 2];
        unsigned int w1 = c[4 * ks2 + 1], w3 = c[4 * ks2 + 3];
        asm("v_permlane32_swap_b32 %0, %1" : "+v"(w0), "+v"(w2));
        asm("v_permlane32_swap_b32 %0, %1" : "+v"(w1), "+v"(w3));
        uintx4 paw; paw[0] = w0; paw[1] = w1; paw[2] = w2; paw[3] = w3;
        const bf16x8 pa = __builtin_bit_cast(bf16x8, paw);

        const int ks = kvb * 2 + ks2;        // 16-kv step within tile
        __builtin_amdgcn_s_setprio(1);
        #pragma unroll
        for (int nb = 0; nb < 2; ++nb) {
          const int ch = ((ks << 1) | hi) ^ (l31 & 7);
          const bf16x8 vf = __builtin_bit_cast(bf16x8,
              *(const short8*)&Vc[(nb * 32 + l31) * 64 + (ch << 3)]);
          ctx[nb] = __builtin_amdgcn_mfma_f32_32x32x16_bf16(pa, vf, ctx[nb], 0, 0, 0);
        }
        __builtin_amdgcn_s_setprio(0);
      }
    }
  }

  // ---- lsum hi-half combine (within wave). Partner value: sb (hi=0) / sa (hi=1).
  float sa = lsumv, sb = lsumv;
  asm("v_permlane32_swap_b32 %0, %1" : "+v"(sa), "+v"(sb));
  const float tot = lsumv + (hi ? sa : sb);   // this half's full column sum, q = q0+l31

  // ---- in-block kv-half combine via LDS overlay ----
  __syncthreads();                            // all waves done reading KsB/VtB
  if (kh == 1) {
    #pragma unroll
    for (int r = 0; r < 16; ++r)
      #pragma unroll
      for (int nb = 0; nb < 2; ++nb)
        ctxL[(nb * 16 + r) * 256 + wid * 64 + lane] = ctx[nb][r];   // lane-contiguous
    if (hi == 0) lsumL[wid * 32 + l31] = tot;
  }
  __syncthreads();
  if (kh == 0) {
    // combine per-column lsum, redistribute to C-row layout (wave-local, in-order DS)
    if (hi == 0) lsumL[128 + wid * 32 + l31] = tot + lsumL[wid * 32 + l31];
    #pragma unroll
    for (int r = 0; r < 16; ++r) {
      const int wr = (r & 3) + 8 * (r >> 2) + 4 * hi;
      const float inv = 1.0f / lsumL[128 + wid * 32 + wr];
      const int qrow = q0 + wr;
      #pragma unroll
      for (int nb = 0; nb < 2; ++nb) {
        const int hd = nb * 32 + l31;
        const float val = (ctx[nb][r] + ctxL[(nb * 16 + r) * 256 + wid * 64 + lane]) * inv;
        out[((size_t)bh * Ss + qrow) * 64 + hd] = val;                             // context
        out[CTX_ELEMS + (((size_t)(b * Ss + qrow)) << 10) + (h << 6) + hd] = val;  // attn_output
      }
    }
  }
}

// ---------------------------------------------------------------------------
// Fallback flash attention (256 threads, full kv per block) — small-ws path.
// ---------------------------------------------------------------------------
__global__ __launch_bounds__(256, 4) void attn_fwd_fb(
    const unsigned short* __restrict__ Qw, const unsigned short* __restrict__ Kw,
    const unsigned short* __restrict__ Vw, float* __restrict__ out)
{
  __shared__ __align__(16) unsigned short Ks[2][64 * 64];
  __shared__ __align__(16) unsigned short Vt[2][64 * 64];
  __shared__ float Ld[4][32];

  const int id  = blockIdx.y * 16 + blockIdx.x;
  const int swz = (id & 7) * 64 + (id >> 3);
  const int qb  = swz & 15, bh = swz >> 4;
  const int b   = bh >> 4, h = bh & 15;

  const int t = threadIdx.x, wid = t >> 6, lane = t & 63;
  const int l31 = lane & 31, hi = lane >> 5;
  const unsigned short* Qb = Qw + (size_t)bh * (Ss * HD);
  const unsigned short* Kb = Kw + (size_t)bh * (Ss * HD);
  const unsigned short* Vg = Vw + (size_t)(h * 64) * Mrows + b * Ss;
  const int q0 = qb * 128 + wid * 32;

  bf16x8 qf[4];
  #pragma unroll
  for (int hs = 0; hs < 4; ++hs)
    qf[hs] = __builtin_bit_cast(bf16x8,
        *(const short8*)(Qb + (size_t)(q0 + l31) * 64 + hs * 16 + hi * 8));

  floatx16 ctx[2];
  ctx[0] = 0.0f; ctx[1] = 0.0f;
  float lsumv = 0.0f;

  const int rl = lane >> 3;
  const int cs = (lane & 7) ^ rl;
  auto stage = [&](int T) {
    const int kv0 = T * 64, buf = T & 1;
    #pragma unroll
    for (int i = 0; i < 2; ++i) {
      const int row = wid * 16 + i * 8 + rl;
      gload16(Kb + (size_t)(kv0 + row) * 64 + cs * 8, &Ks[buf][(wid * 16 + i * 8) * 64]);
      gload16(Vg + (size_t)row * Mrows + kv0 + cs * 8, &Vt[buf][(wid * 16 + i * 8) * 64]);
    }
  };

  stage(0);

  for (int it = 0; it < 32; ++it) {
    const int cur = it & 1;
    __syncthreads();
    if (it + 1 < 32) stage(it + 1);

    #pragma unroll
    for (int kvb = 0; kvb < 2; ++kvb) {
      floatx16 s = 0.0f;
      #pragma unroll
      for (int hs = 0; hs < 4; ++hs) {
        const int ch = ((hs << 1) | hi) ^ (l31 & 7);
        const bf16x8 kf = __builtin_bit_cast(bf16x8,
            *(const short8*)&Ks[cur][(kvb * 32 + l31) * 64 + (ch << 3)]);
        s = __builtin_amdgcn_mfma_f32_32x32x16_bf16(kf, qf[hs], s, 0, 0, 0);
      }
      float p[16];
      #pragma unroll
      for (int r = 0; r < 16; ++r) { p[r] = fexp2(s[r]); lsumv += p[r]; }
      unsigned int c[8];
      #pragma unroll
      for (int i = 0; i < 8; ++i)
        asm("v_cvt_pk_bf16_f32 %0, %1, %2" : "=v"(c[i]) : "v"(p[2 * i]), "v"(p[2 * i + 1]));
      #pragma unroll
      for (int ks2 = 0; ks2 < 2; ++ks2) {
        unsigned int w0 = c[4 * ks2 + 0], w2 = c[4 * ks2 + 2];
        unsigned int w1 = c[4 * ks2 + 1], w3 = c[4 * ks2 + 3];
        asm("v_permlane32_swap_b32 %0, %1" : "+v"(w0), "+v"(w2));
        asm("v_permlane32_swap_b32 %0, %1" : "+v"(w1), "+v"(w3));
        uintx4 paw; paw[0] = w0; paw[1] = w1; paw[2] = w2; paw[3] = w3;
        const bf16x8 pa = __builtin_bit_cast(bf16x8, paw);
        const int ks = kvb * 2 + ks2;
        #pragma unroll
        for (int nb = 0; nb < 2; ++nb) {
          const int ch = ((ks << 1) | hi) ^ (l31 & 7);
          const bf16x8 vf = __builtin_bit_cast(bf16x8,
              *(const short8*)&Vt[cur][(nb * 32 + l31) * 64 + (ch << 3)]);
          ctx[nb] = __builtin_amdgcn_mfma_f32_32x32x16_bf16(pa, vf, ctx[nb], 0, 0, 0);
        }
      }
    }
  }

  float sa = lsumv, sb = lsumv;
  asm("v_permlane32_swap_b32 %0, %1" : "+v"(sa), "+v"(sb));
  const float tot = lsumv + (hi ? sa : sb);

  if (hi == 0) Ld[wid][l31] = tot;
  #pragma unroll
  for (int r = 0; r < 16; ++r) {
    const int wr = (r & 3) + 8 * (r >> 2) + 4 * hi;
    const float inv = 1.0f / Ld[wid][wr];
    const int qrow = q0 + wr;
    #pragma unroll
    for (int nb = 0; nb < 2; ++nb) {
      const int hd = nb * 32 + l31;
      const float val = ctx[nb][r] * inv;
      out[((size_t)bh * Ss + qrow) * 64 + hd] = val;
      out[CTX_ELEMS + (((size_t)(b * Ss + qrow)) << 10) + (h << 6) + hd] = val;
    }
  }
}

// ---------------------------------------------------------------------------
extern "C" void kernel_launch(void* const* d_in, const int* in_sizes, int n_in,
                              void* d_out, int out_size, void* d_ws, size_t ws_size,
                              hipStream_t stream) {
  const float* q  = (const float*)d_in[0];
  const float* k  = (const float*)d_in[1];
  const float* v  = (const float*)d_in[2];
  const float* wq = (const float*)d_in[3];
  const float* bq = (const float*)d_in[4];
  const float* wk = (const float*)d_in[5];
  const float* bk = (const float*)d_in[6];
  const float* wv = (const float*)d_in[7];
  const float* bv = (const float*)d_in[8];
  unsigned short* ws = (unsigned short*)d_ws;
  float* out = (float*)d_out;

  if (ws_size >= WS_NEED) {
    convert_bf16<<<dim3(256, 6), 256, 0, stream>>>(q, k, v, wq, wk, wv, ws);
    qkv_gemm_bf16<<<dim3(256, 3), 256, 0, stream>>>(ws, bq, bk, bv, ws + OFF_O);
    attn_fwd8<<<dim3(16, 32), 512, 0, stream>>>(
        ws + OFF_O, ws + OFF_O + XE, ws + OFF_O + 2 * XE, out);
  } else {
    qkv_gemm_f32<<<dim3(256, 3), 256, 0, stream>>>(q, k, v, wq, wk, wv, bq, bk, bv, ws);
    attn_fwd_fb<<<dim3(16, 32), 256, 0, stream>>>(ws, ws + XE, ws + 2 * XE, out);
  }
}